// Round 13
// baseline (288.155 us; speedup 1.0000x reference)
//
#include <hip/hip_runtime.h>
#include <hip/hip_bf16.h>
#include <math.h>

// Problem constants (match reference)
#define B_   2
#define T_   2048
#define TOK_ 512
#define POS_ 512
#define H_   16
#define D_   64
#define KVH_ 4

typedef float f32x4 __attribute__((ext_vector_type(4)));
typedef short bf16x8 __attribute__((ext_vector_type(8)));
typedef unsigned short u16;
typedef u16 u16x4 __attribute__((ext_vector_type(4)));
typedef u16 u16x8 __attribute__((ext_vector_type(8)));

// RNE float -> bf16 bits
__device__ inline u16 f2bf(float f) {
    union { float f; unsigned u; } v; v.f = f;
    unsigned r = v.u + 0x7FFFu + ((v.u >> 16) & 1u);
    return (u16)(r >> 16);
}

// ---------------------------------------------------------------------------
// x (fp32, M x 1024) -> xb (bf16). 4 elems/thread.
// ---------------------------------------------------------------------------
__global__ void cvt_x(const float* __restrict__ X, u16* __restrict__ Xb) {
    int i = (blockIdx.x * 256 + threadIdx.x) * 4;
    f32x4 v = *reinterpret_cast<const f32x4*>(X + i);
    u16x4 o;
    #pragma unroll
    for (int u = 0; u < 4; ++u) o[u] = f2bf(v[u]);
    *reinterpret_cast<u16x4*>(Xb + i) = o;
}

// ---------------------------------------------------------------------------
// W (K x N fp32, row-major) -> WT (N x K bf16). 32x32 LDS tile.
// ---------------------------------------------------------------------------
__global__ void transp_k(const float* __restrict__ W, u16* __restrict__ WT,
                         int K, int N) {
    __shared__ float t[32][33];
    const int tid = threadIdx.x;
    const int k0 = blockIdx.y * 32, n0 = blockIdx.x * 32;
    const int r = tid >> 3, c4 = (tid & 7) * 4;
    f32x4 v = *reinterpret_cast<const f32x4*>(W + (size_t)(k0 + r) * N + n0 + c4);
    #pragma unroll
    for (int u = 0; u < 4; ++u) t[r][c4 + u] = v[u];
    __syncthreads();
    u16x4 o;
    #pragma unroll
    for (int u = 0; u < 4; ++u) o[u] = f2bf(t[c4 + u][r]);
    *reinterpret_cast<u16x4*>(WT + (size_t)(n0 + r) * K + k0 + c4) = o;
}

// ---------------------------------------------------------------------------
// bf16 MFMA GEMM: C[M,N] = A[M,K] @ W[K,N], W given pre-transposed (Bt: N x K).
// 128x128 tile, BK=32, 4 waves in 2x2, each wave a 64x64 sub-tile of 4x4
// 16x16 frags. Fragment mapping HW-validated (rounds 3/10):
//   A: row=lane&15, k=(lane>>4)*8+e ; B: col=lane&15, same k ;
//   C/D: col=lane&15, row=(lane>>4)*4+j.
// LDS rows stride 80 B (16B-aligned, breaks the stride-64B bank geometry).
// MODE 0: fp32 write to out[m][1024] (Wo GEMM)
// MODE 1: phase-rotate pairs via __shfl_xor(.,1), write bf16 (B,H,T,D)
// MODE 2: write bf16 (B,KVH,T,D)
// ---------------------------------------------------------------------------
template<int MODE>
__global__ __launch_bounds__(256, 2)
void mfma_gemm(const u16* __restrict__ A, int lda, int aoff,
               const u16* __restrict__ Bt, int Ktot,
               void* __restrict__ Cout, const float* __restrict__ angles)
{
    __shared__ __align__(16) unsigned char lds[20480];
    unsigned char* As = lds;            // 128 rows x 32 bf16, stride 80 B
    unsigned char* Bs = lds + 10240;    // 128 rows x 32 bf16, stride 80 B

    const int tid  = threadIdx.x;
    const int lane = tid & 63;
    const int w    = tid >> 6;
    const int wm   = w >> 1, wn = w & 1;
    const int lr   = lane & 15, lg = lane >> 4;
    const int m0   = blockIdx.y * 128;
    const int n0   = blockIdx.x * 128;

    f32x4 acc[4][4] = {};

    for (int k0 = 0; k0 < Ktot; k0 += 32) {
        __syncthreads();
        #pragma unroll
        for (int p = 0; p < 2; ++p) {
            int lin = tid + p * 256;          // 0..511
            int row = lin >> 2;               // 0..127
            int kc  = (lin & 3) * 8;          // 0,8,16,24
            u16x8 av = *reinterpret_cast<const u16x8*>(
                A + (size_t)(m0 + row) * lda + aoff + k0 + kc);
            *reinterpret_cast<u16x8*>(As + row * 80 + kc * 2) = av;
            u16x8 bv = *reinterpret_cast<const u16x8*>(
                Bt + (size_t)(n0 + row) * Ktot + k0 + kc);
            *reinterpret_cast<u16x8*>(Bs + row * 80 + kc * 2) = bv;
        }
        __syncthreads();

        bf16x8 af[4], bfr[4];
        #pragma unroll
        for (int mt = 0; mt < 4; ++mt)
            af[mt] = *reinterpret_cast<bf16x8*>(
                As + (wm * 64 + mt * 16 + lr) * 80 + lg * 16);
        #pragma unroll
        for (int nt = 0; nt < 4; ++nt)
            bfr[nt] = *reinterpret_cast<bf16x8*>(
                Bs + (wn * 64 + nt * 16 + lr) * 80 + lg * 16);
        #pragma unroll
        for (int mt = 0; mt < 4; ++mt)
            #pragma unroll
            for (int nt = 0; nt < 4; ++nt)
                acc[mt][nt] = __builtin_amdgcn_mfma_f32_16x16x32_bf16(
                    af[mt], bfr[nt], acc[mt][nt], 0, 0, 0);
    }

    // Epilogue. m = m0+wm*64+mt*16+lg*4+j ; n = n0+wn*64+nt*16+lr
    #pragma unroll
    for (int nt = 0; nt < 4; ++nt) {
        const int nbase = n0 + wn * 64 + nt * 16;   // multiple of 16
        float ca = 0.f, sa = 0.f;
        if (MODE == 1) {
            const int h = nbase >> 6;               // constant across lr (<64)
            ca = cosf(angles[h]);
            sa = sinf(angles[h]);
        }
        #pragma unroll
        for (int mt = 0; mt < 4; ++mt) {
            #pragma unroll
            for (int j = 0; j < 4; ++j) {
                const int m = m0 + wm * 64 + mt * 16 + lg * 4 + j;
                const int n = nbase + lr;
                const float v = acc[mt][nt][j];
                if (MODE == 0) {
                    ((float*)Cout)[(size_t)m * (TOK_ + POS_) + n] = v;
                } else if (MODE == 1) {
                    const float p = __shfl_xor(v, 1);   // partner column n^1
                    const float o = (lr & 1) ? (p * sa + v * ca)
                                             : (v * ca - p * sa);
                    const int b = m >> 11, t = m & (T_ - 1);
                    const int h = n >> 6, d = n & 63;
                    ((u16*)Cout)[(((size_t)(b * H_ + h)) * T_ + t) * D_ + d] = f2bf(o);
                } else {
                    const int b = m >> 11, t = m & (T_ - 1);
                    const int h = n >> 6, d = n & 63;
                    ((u16*)Cout)[(((size_t)(b * KVH_ + h)) * T_ + t) * D_ + d] = f2bf(v);
                }
            }
        }
    }
}

// ---------------------------------------------------------------------------
// MFMA bf16 flash attention (causal, ALiBi, "+1" denominator).
// ROUND 12 CHANGE: LPT scheduling for concurrency. Round-12 counters:
// occupancy 20.7% == the 2-blocks/CU cap of the 512-block paired grid;
// VALUBusy 36% (busiest pipe) -> more resident waves, not better balance,
// is the lever. One q-tile per block again (grid 32x32 = 1024 blocks =
// 4/CU) but BIG TILES FIRST: qt = 31 - blockIdx.x, so dynamic dispatch
// fills CUs with long blocks early (LPT; round-10's 13.6% occupancy was
// ascending order = big-last tail pathology). launch_bounds(256,4)
// permits 4 blocks/CU (LDS 24.5KB -> 6; VGPR 76 -> fits 128 cap).
// Per-q-row arithmetic IDENTICAL to validated rounds 10/12.
// ---------------------------------------------------------------------------
__global__ __launch_bounds__(256, 4)
void flash_mfma(const u16* __restrict__ Q, const u16* __restrict__ K,
                const u16* __restrict__ V, const float* __restrict__ slopes,
                u16* __restrict__ O)
{
    __shared__ __align__(16) unsigned char lds[24576];
    unsigned char* Ks = lds;              // K tile: [key][d]  64x128B
    unsigned char* Vt = lds + 8192;       // V tile transposed: [d][key] 64x128B
    unsigned char* Ps = lds + 16384;      // P tiles: per-wave [16][64] bf16

    const int tid  = threadIdx.x;
    const int lane = tid & 63;
    const int w    = tid >> 6;
    const int lr   = lane & 15;
    const int lg   = lane >> 4;

    const int bh  = blockIdx.y;
    const int b   = bh >> 4;
    const int h   = bh & 15;
    const int kvh = h >> 2;              // GQA: h // (H/KVH)
    const int qt  = (T_ / 64 - 1) - blockIdx.x;   // LPT: longest first
    const int q0  = qt * 64;

    const float slope = expf(slopes[h]);

    const u16* Qp = Q + (((size_t)(b * H_ + h)) * T_ + q0 + w * 16) * D_;
    const u16* Kp = K + ((size_t)(b * KVH_ + kvh)) * T_ * D_;
    const u16* Vp = V + ((size_t)(b * KVH_ + kvh)) * T_ * D_;

    const bf16x8 qa0 = *reinterpret_cast<const bf16x8*>(Qp + lr * D_ + lg * 8);
    const bf16x8 qa1 = *reinterpret_cast<const bf16x8*>(Qp + lr * D_ + 32 + lg * 8);

    f32x4 acc[4] = {};
    float mrow[4], lrow[4];
    #pragma unroll
    for (int j = 0; j < 4; ++j) { mrow[j] = -INFINITY; lrow[j] = 0.f; }

    unsigned char* Pw = Ps + w * 2048;   // 16 rows x 128 B, wave-private

    for (int jt = 0; jt <= qt; ++jt) {
        const int kv0 = jt * 64;
        __syncthreads();                 // all waves done reading previous tile
        #pragma unroll
        for (int it = 0; it < 2; ++it) {
            int lin = tid + it * 256;
            int row = lin >> 3;
            int c16 = (lin & 7) * 16;
            u16x8 kv = *reinterpret_cast<const u16x8*>(
                Kp + (size_t)(kv0 + row) * D_ + (lin & 7) * 8);
            *reinterpret_cast<u16x8*>(Ks + ((row * 128 + c16) ^ ((row & 7) << 4))) = kv;
            int key = lin & 63;
            int d8  = (lin >> 6) * 8;
            u16x8 vv = *reinterpret_cast<const u16x8*>(
                Vp + (size_t)(kv0 + key) * D_ + d8);
            #pragma unroll
            for (int e = 0; e < 8; ++e) {
                int d = d8 + e;
                *reinterpret_cast<u16*>(
                    Vt + ((d * 128 + key * 2) ^ ((d & 7) << 4))) = (u16)vv[e];
            }
        }
        __syncthreads();

        f32x4 s[4];
        #pragma unroll
        for (int n = 0; n < 4; ++n) {
            int krow = n * 16 + lr;
            int swz  = (krow & 7) << 4;
            bf16x8 kb0 = *reinterpret_cast<bf16x8*>(Ks + ((krow * 128 + lg * 16) ^ swz));
            bf16x8 kb1 = *reinterpret_cast<bf16x8*>(Ks + ((krow * 128 + 64 + lg * 16) ^ swz));
            f32x4 z = {};
            z    = __builtin_amdgcn_mfma_f32_16x16x32_bf16(qa0, kb0, z, 0, 0, 0);
            s[n] = __builtin_amdgcn_mfma_f32_16x16x32_bf16(qa1, kb1, z, 0, 0, 0);
        }

        const int qbase = q0 + w * 16 + lg * 4;
        #pragma unroll
        for (int j = 0; j < 4; ++j) {
            const int qr = qbase + j;
            float a[4];
            float tmax = -INFINITY;
            #pragma unroll
            for (int n = 0; n < 4; ++n) {
                int kg = kv0 + n * 16 + lr;
                float vsc = s[n][j] * 0.125f + slope * (float)(qr - kg);
                vsc = (kg <= qr) ? vsc : -INFINITY;
                a[n] = vsc;
                tmax = fmaxf(tmax, vsc);
            }
            #pragma unroll
            for (int off = 1; off < 16; off <<= 1)
                tmax = fmaxf(tmax, __shfl_xor(tmax, off));
            const float mnew = fmaxf(mrow[j], tmax);
            const float sc   = __expf(mrow[j] - mnew);   // -inf -> 0 first tile
            float rsum = 0.f;
            u16 pb[4];
            #pragma unroll
            for (int n = 0; n < 4; ++n) {
                float p = __expf(a[n] - mnew);           // masked -> 0
                rsum += p;
                pb[n] = f2bf(p);
            }
            #pragma unroll
            for (int off = 1; off < 16; off <<= 1)
                rsum += __shfl_xor(rsum, off);
            lrow[j] = lrow[j] * sc + rsum;
            mrow[j] = mnew;
            #pragma unroll
            for (int dt = 0; dt < 4; ++dt) acc[dt][j] *= sc;
            const int prow = lg * 4 + j;
            #pragma unroll
            for (int n = 0; n < 4; ++n)
                *reinterpret_cast<u16*>(
                    Pw + ((prow * 128 + (n * 16 + lr) * 2) ^ ((prow & 7) << 4))) = pb[n];
        }

        #pragma unroll
        for (int kh = 0; kh < 2; ++kh) {
            bf16x8 pa = *reinterpret_cast<bf16x8*>(
                Pw + ((lr * 128 + kh * 64 + lg * 16) ^ ((lr & 7) << 4)));
            #pragma unroll
            for (int dt = 0; dt < 4; ++dt) {
                int drow = dt * 16 + lr;
                bf16x8 vb = *reinterpret_cast<bf16x8*>(
                    Vt + ((drow * 128 + kh * 64 + lg * 16) ^ ((drow & 7) << 4)));
                acc[dt] = __builtin_amdgcn_mfma_f32_16x16x32_bf16(pa, vb, acc[dt], 0, 0, 0);
            }
        }
    }

    // epilogue: denom = 1 + l, write bf16 (B,T,H*D)
    u16* Op = O + ((size_t)b * T_ + q0 + w * 16) * (H_ * D_) + h * 64;
    #pragma unroll
    for (int j = 0; j < 4; ++j) {
        const float inv = 1.0f / (1.0f + lrow[j]);
        const int r = lg * 4 + j;
        #pragma unroll
        for (int dt = 0; dt < 4; ++dt)
            Op[(size_t)r * (H_ * D_) + dt * 16 + lr] = f2bf(acc[dt][j] * inv);
    }
}

// ---------------------------------------------------------------------------
// Launcher. ws layout (u16 elems): xb 4M | Qb 4M | Kb 1M | Vb 1M | AttO 4M |
// WqT 512K | WkT 128K | WvT 128K | WoT 1M  (~31.7 MB). All regions written
// every call before read (ws is re-poisoned each timed launch).
// ---------------------------------------------------------------------------
extern "C" void kernel_launch(void* const* d_in, const int* in_sizes, int n_in,
                              void* d_out, int out_size, void* d_ws, size_t ws_size,
                              hipStream_t stream)
{
    const float* x      = (const float*)d_in[0];
    const float* Wq     = (const float*)d_in[1];
    const float* Wk     = (const float*)d_in[2];
    const float* Wv     = (const float*)d_in[3];
    const float* Wo     = (const float*)d_in[4];
    const float* ang    = (const float*)d_in[5];
    const float* slopes = (const float*)d_in[6];
    float* out = (float*)d_out;

    u16* xb   = (u16*)d_ws;
    u16* Qb   = xb   + (size_t)4096 * 1024;
    u16* Kb   = Qb   + (size_t)B_ * H_ * T_ * D_;
    u16* Vb   = Kb   + (size_t)B_ * KVH_ * T_ * D_;
    u16* AttO = Vb   + (size_t)B_ * KVH_ * T_ * D_;
    u16* WqT  = AttO + (size_t)4096 * 1024;
    u16* WkT  = WqT  + (size_t)1024 * 512;
    u16* WvT  = WkT  + (size_t)256 * 512;
    u16* WoT  = WvT  + (size_t)256 * 512;

    // Prologue: convert x, transpose+convert weights
    cvt_x<<<4096, 256, 0, stream>>>(x, xb);
    transp_k<<<dim3(1024 / 32, 512 / 32), 256, 0, stream>>>(Wq, WqT, 512, 1024);
    transp_k<<<dim3(256 / 32, 512 / 32), 256, 0, stream>>>(Wk, WkT, 512, 256);
    transp_k<<<dim3(256 / 32, 512 / 32), 256, 0, stream>>>(Wv, WvT, 512, 256);
    transp_k<<<dim3(1024 / 32, 1024 / 32), 256, 0, stream>>>(Wo, WoT, 1024, 1024);

    // Projections (bf16 MFMA)
    mfma_gemm<1><<<dim3(8, 32), 256, 0, stream>>>(xb, 1024, 512, WqT, 512, Qb, ang);
    mfma_gemm<2><<<dim3(2, 32), 256, 0, stream>>>(xb, 1024, 512, WkT, 512, Kb, nullptr);
    mfma_gemm<2><<<dim3(2, 32), 256, 0, stream>>>(xb, 1024, 0,   WvT, 512, Vb, nullptr);

    // Flash attention (LPT: 1 q-tile/block, longest first) -> AttO bf16
    flash_mfma<<<dim3(T_ / 64, B_ * H_), 256, 0, stream>>>(Qb, Kb, Vb, slopes, AttO);

    // out = AttO @ Wo (bf16 MFMA, fp32 out)
    mfma_gemm<0><<<dim3(8, 32), 256, 0, stream>>>(AttO, 1024, 0, WoT, 1024, out, nullptr);
}

// Round 14
// 236.058 us; speedup vs baseline: 1.2207x; 1.2207x over previous
//
#include <hip/hip_runtime.h>
#include <hip/hip_bf16.h>
#include <math.h>

// Problem constants (match reference)
#define B_   2
#define T_   2048
#define TOK_ 512
#define POS_ 512
#define H_   16
#define D_   64
#define KVH_ 4

typedef float f32x4 __attribute__((ext_vector_type(4)));
typedef short bf16x8 __attribute__((ext_vector_type(8)));
typedef unsigned short u16;
typedef u16 u16x4 __attribute__((ext_vector_type(4)));
typedef u16 u16x8 __attribute__((ext_vector_type(8)));

// RNE float -> bf16 bits
__device__ inline u16 f2bf(float f) {
    union { float f; unsigned u; } v; v.f = f;
    unsigned r = v.u + 0x7FFFu + ((v.u >> 16) & 1u);
    return (u16)(r >> 16);
}

// ---------------------------------------------------------------------------
// x (fp32, M x 1024) -> xb (bf16). 4 elems/thread.
// ---------------------------------------------------------------------------
__global__ void cvt_x(const float* __restrict__ X, u16* __restrict__ Xb) {
    int i = (blockIdx.x * 256 + threadIdx.x) * 4;
    f32x4 v = *reinterpret_cast<const f32x4*>(X + i);
    u16x4 o;
    #pragma unroll
    for (int u = 0; u < 4; ++u) o[u] = f2bf(v[u]);
    *reinterpret_cast<u16x4*>(Xb + i) = o;
}

// ---------------------------------------------------------------------------
// W (K x N fp32, row-major) -> WT (N x K bf16). 32x32 LDS tile.
// ---------------------------------------------------------------------------
__global__ void transp_k(const float* __restrict__ W, u16* __restrict__ WT,
                         int K, int N) {
    __shared__ float t[32][33];
    const int tid = threadIdx.x;
    const int k0 = blockIdx.y * 32, n0 = blockIdx.x * 32;
    const int r = tid >> 3, c4 = (tid & 7) * 4;
    f32x4 v = *reinterpret_cast<const f32x4*>(W + (size_t)(k0 + r) * N + n0 + c4);
    #pragma unroll
    for (int u = 0; u < 4; ++u) t[r][c4 + u] = v[u];
    __syncthreads();
    u16x4 o;
    #pragma unroll
    for (int u = 0; u < 4; ++u) o[u] = f2bf(t[c4 + u][r]);
    *reinterpret_cast<u16x4*>(WT + (size_t)(n0 + r) * K + k0 + c4) = o;
}

// ---------------------------------------------------------------------------
// bf16 MFMA GEMM: C[M,N] = A[M,K] @ W[K,N], W given pre-transposed (Bt: N x K).
// 128x128 tile, BK=32, 4 waves in 2x2, each wave a 64x64 sub-tile of 4x4
// 16x16 frags. Fragment mapping HW-validated (rounds 3/10):
//   A: row=lane&15, k=(lane>>4)*8+e ; B: col=lane&15, same k ;
//   C/D: col=lane&15, row=(lane>>4)*4+j.
// LDS rows stride 80 B (16B-aligned, breaks the stride-64B bank geometry).
// MODE 0: fp32 write to out[m][1024] (Wo GEMM)
// MODE 1: phase-rotate pairs via __shfl_xor(.,1), write bf16 (B,H,T,D)
// MODE 2: write bf16 (B,KVH,T,D)
// ---------------------------------------------------------------------------
template<int MODE>
__global__ __launch_bounds__(256, 2)
void mfma_gemm(const u16* __restrict__ A, int lda, int aoff,
               const u16* __restrict__ Bt, int Ktot,
               void* __restrict__ Cout, const float* __restrict__ angles)
{
    __shared__ __align__(16) unsigned char lds[20480];
    unsigned char* As = lds;            // 128 rows x 32 bf16, stride 80 B
    unsigned char* Bs = lds + 10240;    // 128 rows x 32 bf16, stride 80 B

    const int tid  = threadIdx.x;
    const int lane = tid & 63;
    const int w    = tid >> 6;
    const int wm   = w >> 1, wn = w & 1;
    const int lr   = lane & 15, lg = lane >> 4;
    const int m0   = blockIdx.y * 128;
    const int n0   = blockIdx.x * 128;

    f32x4 acc[4][4] = {};

    for (int k0 = 0; k0 < Ktot; k0 += 32) {
        __syncthreads();
        #pragma unroll
        for (int p = 0; p < 2; ++p) {
            int lin = tid + p * 256;          // 0..511
            int row = lin >> 2;               // 0..127
            int kc  = (lin & 3) * 8;          // 0,8,16,24
            u16x8 av = *reinterpret_cast<const u16x8*>(
                A + (size_t)(m0 + row) * lda + aoff + k0 + kc);
            *reinterpret_cast<u16x8*>(As + row * 80 + kc * 2) = av;
            u16x8 bv = *reinterpret_cast<const u16x8*>(
                Bt + (size_t)(n0 + row) * Ktot + k0 + kc);
            *reinterpret_cast<u16x8*>(Bs + row * 80 + kc * 2) = bv;
        }
        __syncthreads();

        bf16x8 af[4], bfr[4];
        #pragma unroll
        for (int mt = 0; mt < 4; ++mt)
            af[mt] = *reinterpret_cast<bf16x8*>(
                As + (wm * 64 + mt * 16 + lr) * 80 + lg * 16);
        #pragma unroll
        for (int nt = 0; nt < 4; ++nt)
            bfr[nt] = *reinterpret_cast<bf16x8*>(
                Bs + (wn * 64 + nt * 16 + lr) * 80 + lg * 16);
        #pragma unroll
        for (int mt = 0; mt < 4; ++mt)
            #pragma unroll
            for (int nt = 0; nt < 4; ++nt)
                acc[mt][nt] = __builtin_amdgcn_mfma_f32_16x16x32_bf16(
                    af[mt], bfr[nt], acc[mt][nt], 0, 0, 0);
    }

    // Epilogue. m = m0+wm*64+mt*16+lg*4+j ; n = n0+wn*64+nt*16+lr
    #pragma unroll
    for (int nt = 0; nt < 4; ++nt) {
        const int nbase = n0 + wn * 64 + nt * 16;   // multiple of 16
        float ca = 0.f, sa = 0.f;
        if (MODE == 1) {
            const int h = nbase >> 6;               // constant across lr (<64)
            ca = cosf(angles[h]);
            sa = sinf(angles[h]);
        }
        #pragma unroll
        for (int mt = 0; mt < 4; ++mt) {
            #pragma unroll
            for (int j = 0; j < 4; ++j) {
                const int m = m0 + wm * 64 + mt * 16 + lg * 4 + j;
                const int n = nbase + lr;
                const float v = acc[mt][nt][j];
                if (MODE == 0) {
                    ((float*)Cout)[(size_t)m * (TOK_ + POS_) + n] = v;
                } else if (MODE == 1) {
                    const float p = __shfl_xor(v, 1);   // partner column n^1
                    const float o = (lr & 1) ? (p * sa + v * ca)
                                             : (v * ca - p * sa);
                    const int b = m >> 11, t = m & (T_ - 1);
                    const int h = n >> 6, d = n & 63;
                    ((u16*)Cout)[(((size_t)(b * H_ + h)) * T_ + t) * D_ + d] = f2bf(o);
                } else {
                    const int b = m >> 11, t = m & (T_ - 1);
                    const int h = n >> 6, d = n & 63;
                    ((u16*)Cout)[(((size_t)(b * KVH_ + h)) * T_ + t) * D_ + d] = f2bf(v);
                }
            }
        }
    }
}

// ---------------------------------------------------------------------------
// Global -> register staging for one 64-key K/V tile (256 threads).
// Thread mapping identical to the validated round-10/12 staging.
// ---------------------------------------------------------------------------
__device__ inline void stage_load(const u16* __restrict__ Kp,
                                  const u16* __restrict__ Vp,
                                  int kv0, int tid,
                                  u16x8* kreg, u16x8* vreg)
{
    #pragma unroll
    for (int it = 0; it < 2; ++it) {
        int lin = tid + it * 256;
        int row = lin >> 3;
        kreg[it] = *reinterpret_cast<const u16x8*>(
            Kp + (size_t)(kv0 + row) * D_ + (lin & 7) * 8);
        int key = lin & 63;
        int d8  = (lin >> 6) * 8;
        vreg[it] = *reinterpret_cast<const u16x8*>(
            Vp + (size_t)(kv0 + key) * D_ + d8);
    }
}

// Register -> LDS staging (XOR-swizzled; K row-major, V transposed).
__device__ inline void stage_write(unsigned char* __restrict__ Ksb,
                                   unsigned char* __restrict__ Vtb,
                                   int tid, const u16x8* kreg, const u16x8* vreg)
{
    #pragma unroll
    for (int it = 0; it < 2; ++it) {
        int lin = tid + it * 256;
        int row = lin >> 3;
        int c16 = (lin & 7) * 16;
        *reinterpret_cast<u16x8*>(Ksb + ((row * 128 + c16) ^ ((row & 7) << 4))) = kreg[it];
        int key = lin & 63;
        int d8  = (lin >> 6) * 8;
        #pragma unroll
        for (int e = 0; e < 8; ++e) {
            int d = d8 + e;
            *reinterpret_cast<u16*>(
                Vtb + ((d * 128 + key * 2) ^ ((d & 7) << 4))) = (u16)vreg[it][e];
        }
    }
}

// ---------------------------------------------------------------------------
// MFMA bf16 flash attention (causal, ALiBi, "+1" denominator).
// Structure: triangular pairing (round 12, validated 101us: each block does
// q-tiles bx and 31-bx = exactly 33 KV-tile units; grid 16x32 = 512 = 2/CU).
// ROUND 13 LESSON: LPT ordering failed — all-resident grids get STATIC
// round-robin assignment (each CU got 4 same-size blocks, 1:4 imbalance);
// balance must be in the block->work mapping. Pairing stays.
// ROUND 14 CHANGE (T14 + dbuf): K/V staged global->regs right after the
// single per-iteration barrier (latency hides under QK^T/softmax/PV), then
// regs->LDS[other buffer] after compute. 1 barrier/iter (was 2), no exposed
// HBM latency. Per-q-row arithmetic IDENTICAL to rounds 10/12.
// LDS: K dbuf 2x8KB + V dbuf 2x8KB + P 4x2KB = 40KB.
// ---------------------------------------------------------------------------
__global__ __launch_bounds__(256, 2)
void flash_mfma(const u16* __restrict__ Q, const u16* __restrict__ K,
                const u16* __restrict__ V, const float* __restrict__ slopes,
                u16* __restrict__ O)
{
    __shared__ __align__(16) unsigned char lds[40960];
    // [0..16384)   : K buffers (2 x 8192)
    // [16384..32768): V^T buffers (2 x 8192)
    // [32768..40960): P tiles, per-wave 2048
    unsigned char* Ps = lds + 32768;

    const int tid  = threadIdx.x;
    const int lane = tid & 63;
    const int w    = tid >> 6;
    const int lr   = lane & 15;
    const int lg   = lane >> 4;

    const int bh  = blockIdx.y;
    const int b   = bh >> 4;
    const int h   = bh & 15;
    const int kvh = h >> 2;              // GQA: h // (H/KVH)

    const float slope = expf(slopes[h]);

    const u16* Kp = K + ((size_t)(b * KVH_ + kvh)) * T_ * D_;
    const u16* Vp = V + ((size_t)(b * KVH_ + kvh)) * T_ * D_;

    unsigned char* Pw = Ps + w * 2048;   // 16 rows x 128 B, wave-private

    u16x8 kreg[2], vreg[2];
    int cur = 0;

    #pragma unroll 1
    for (int pass = 0; pass < 2; ++pass) {
        const int qt = pass ? (T_ / 64 - 1 - blockIdx.x) : blockIdx.x;
        const int q0 = qt * 64;

        const u16* Qp = Q + (((size_t)(b * H_ + h)) * T_ + q0 + w * 16) * D_;
        const bf16x8 qa0 = *reinterpret_cast<const bf16x8*>(Qp + lr * D_ + lg * 8);
        const bf16x8 qa1 = *reinterpret_cast<const bf16x8*>(Qp + lr * D_ + 32 + lg * 8);

        f32x4 acc[4] = {};
        float mrow[4], lrow[4];
        #pragma unroll
        for (int j = 0; j < 4; ++j) { mrow[j] = -INFINITY; lrow[j] = 0.f; }

        // Pass prologue: stage tile 0 into buffer `cur`.
        stage_load(Kp, Vp, 0, tid, kreg, vreg);
        __syncthreads();                 // prior readers of buffer `cur` done
        stage_write(lds + cur * 8192, lds + 16384 + cur * 8192, tid, kreg, vreg);

        for (int jt = 0; jt <= qt; ++jt) {
            __syncthreads();             // buffer `cur` staging visible to all
            if (jt < qt)                 // issue next tile's loads early (T14)
                stage_load(Kp, Vp, (jt + 1) * 64, tid, kreg, vreg);

            unsigned char* Ks = lds + cur * 8192;
            unsigned char* Vt = lds + 16384 + cur * 8192;
            const int kv0 = jt * 64;

            f32x4 s[4];
            #pragma unroll
            for (int n = 0; n < 4; ++n) {
                int krow = n * 16 + lr;
                int swz  = (krow & 7) << 4;
                bf16x8 kb0 = *reinterpret_cast<bf16x8*>(Ks + ((krow * 128 + lg * 16) ^ swz));
                bf16x8 kb1 = *reinterpret_cast<bf16x8*>(Ks + ((krow * 128 + 64 + lg * 16) ^ swz));
                f32x4 z = {};
                z    = __builtin_amdgcn_mfma_f32_16x16x32_bf16(qa0, kb0, z, 0, 0, 0);
                s[n] = __builtin_amdgcn_mfma_f32_16x16x32_bf16(qa1, kb1, z, 0, 0, 0);
            }

            const int qbase = q0 + w * 16 + lg * 4;
            #pragma unroll
            for (int j = 0; j < 4; ++j) {
                const int qr = qbase + j;
                float a[4];
                float tmax = -INFINITY;
                #pragma unroll
                for (int n = 0; n < 4; ++n) {
                    int kg = kv0 + n * 16 + lr;
                    float vsc = s[n][j] * 0.125f + slope * (float)(qr - kg);
                    vsc = (kg <= qr) ? vsc : -INFINITY;
                    a[n] = vsc;
                    tmax = fmaxf(tmax, vsc);
                }
                #pragma unroll
                for (int off = 1; off < 16; off <<= 1)
                    tmax = fmaxf(tmax, __shfl_xor(tmax, off));
                const float mnew = fmaxf(mrow[j], tmax);
                const float sc   = __expf(mrow[j] - mnew);   // -inf -> 0 first tile
                float rsum = 0.f;
                u16 pb[4];
                #pragma unroll
                for (int n = 0; n < 4; ++n) {
                    float p = __expf(a[n] - mnew);           // masked -> 0
                    rsum += p;
                    pb[n] = f2bf(p);
                }
                #pragma unroll
                for (int off = 1; off < 16; off <<= 1)
                    rsum += __shfl_xor(rsum, off);
                lrow[j] = lrow[j] * sc + rsum;
                mrow[j] = mnew;
                #pragma unroll
                for (int dt = 0; dt < 4; ++dt) acc[dt][j] *= sc;
                const int prow = lg * 4 + j;
                #pragma unroll
                for (int n = 0; n < 4; ++n)
                    *reinterpret_cast<u16*>(
                        Pw + ((prow * 128 + (n * 16 + lr) * 2) ^ ((prow & 7) << 4))) = pb[n];
            }

            #pragma unroll
            for (int kh = 0; kh < 2; ++kh) {
                bf16x8 pa = *reinterpret_cast<bf16x8*>(
                    Pw + ((lr * 128 + kh * 64 + lg * 16) ^ ((lr & 7) << 4)));
                #pragma unroll
                for (int dt = 0; dt < 4; ++dt) {
                    int drow = dt * 16 + lr;
                    bf16x8 vb = *reinterpret_cast<bf16x8*>(
                        Vt + ((drow * 128 + kh * 64 + lg * 16) ^ ((drow & 7) << 4)));
                    acc[dt] = __builtin_amdgcn_mfma_f32_16x16x32_bf16(pa, vb, acc[dt], 0, 0, 0);
                }
            }

            if (jt < qt) {               // write next tile to the other buffer
                stage_write(lds + (cur ^ 1) * 8192, lds + 16384 + (cur ^ 1) * 8192,
                            tid, kreg, vreg);
                cur ^= 1;
            }
        }

        // epilogue: denom = 1 + l, write bf16 (B,T,H*D)
        u16* Op = O + ((size_t)b * T_ + q0 + w * 16) * (H_ * D_) + h * 64;
        #pragma unroll
        for (int j = 0; j < 4; ++j) {
            const float inv = 1.0f / (1.0f + lrow[j]);
            const int r = lg * 4 + j;
            #pragma unroll
            for (int dt = 0; dt < 4; ++dt)
                Op[(size_t)r * (H_ * D_) + dt * 16 + lr] = f2bf(acc[dt][j] * inv);
        }
    }
}

// ---------------------------------------------------------------------------
// Launcher. ws layout (u16 elems): xb 4M | Qb 4M | Kb 1M | Vb 1M | AttO 4M |
// WqT 512K | WkT 128K | WvT 128K | WoT 1M  (~31.7 MB). All regions written
// every call before read (ws is re-poisoned each timed launch).
// ---------------------------------------------------------------------------
extern "C" void kernel_launch(void* const* d_in, const int* in_sizes, int n_in,
                              void* d_out, int out_size, void* d_ws, size_t ws_size,
                              hipStream_t stream)
{
    const float* x      = (const float*)d_in[0];
    const float* Wq     = (const float*)d_in[1];
    const float* Wk     = (const float*)d_in[2];
    const float* Wv     = (const float*)d_in[3];
    const float* Wo     = (const float*)d_in[4];
    const float* ang    = (const float*)d_in[5];
    const float* slopes = (const float*)d_in[6];
    float* out = (float*)d_out;

    u16* xb   = (u16*)d_ws;
    u16* Qb   = xb   + (size_t)4096 * 1024;
    u16* Kb   = Qb   + (size_t)B_ * H_ * T_ * D_;
    u16* Vb   = Kb   + (size_t)B_ * KVH_ * T_ * D_;
    u16* AttO = Vb   + (size_t)B_ * KVH_ * T_ * D_;
    u16* WqT  = AttO + (size_t)4096 * 1024;
    u16* WkT  = WqT  + (size_t)1024 * 512;
    u16* WvT  = WkT  + (size_t)256 * 512;
    u16* WoT  = WvT  + (size_t)256 * 512;

    // Prologue: convert x, transpose+convert weights
    cvt_x<<<4096, 256, 0, stream>>>(x, xb);
    transp_k<<<dim3(1024 / 32, 512 / 32), 256, 0, stream>>>(Wq, WqT, 512, 1024);
    transp_k<<<dim3(256 / 32, 512 / 32), 256, 0, stream>>>(Wk, WkT, 512, 256);
    transp_k<<<dim3(256 / 32, 512 / 32), 256, 0, stream>>>(Wv, WvT, 512, 256);
    transp_k<<<dim3(1024 / 32, 1024 / 32), 256, 0, stream>>>(Wo, WoT, 1024, 1024);

    // Projections (bf16 MFMA)
    mfma_gemm<1><<<dim3(8, 32), 256, 0, stream>>>(xb, 1024, 512, WqT, 512, Qb, ang);
    mfma_gemm<2><<<dim3(2, 32), 256, 0, stream>>>(xb, 1024, 512, WkT, 512, Kb, nullptr);
    mfma_gemm<2><<<dim3(2, 32), 256, 0, stream>>>(xb, 1024, 0,   WvT, 512, Vb, nullptr);

    // Flash attention (paired tiles + T14 dbuf staging) -> AttO bf16
    flash_mfma<<<dim3(T_ / 128, B_ * H_), 256, 0, stream>>>(Qb, Kb, Vb, slopes, AttO);

    // out = AttO @ Wo (bf16 MFMA, fp32 out)
    mfma_gemm<0><<<dim3(8, 32), 256, 0, stream>>>(AttO, 1024, 0, WoT, 1024, out, nullptr);
}

// Round 15
// 226.754 us; speedup vs baseline: 1.2708x; 1.0410x over previous
//
#include <hip/hip_runtime.h>
#include <hip/hip_bf16.h>
#include <math.h>

// Problem constants (match reference)
#define B_   2
#define T_   2048
#define TOK_ 512
#define POS_ 512
#define H_   16
#define D_   64
#define KVH_ 4

typedef float f32x4 __attribute__((ext_vector_type(4)));
typedef short bf16x8 __attribute__((ext_vector_type(8)));
typedef unsigned short u16;
typedef u16 u16x4 __attribute__((ext_vector_type(4)));
typedef u16 u16x8 __attribute__((ext_vector_type(8)));

// RNE float -> bf16 bits
__device__ inline u16 f2bf(float f) {
    union { float f; unsigned u; } v; v.f = f;
    unsigned r = v.u + 0x7FFFu + ((v.u >> 16) & 1u);
    return (u16)(r >> 16);
}

// ---------------------------------------------------------------------------
// x (fp32, M x 1024) -> xb (bf16). 4 elems/thread.
// ---------------------------------------------------------------------------
__global__ void cvt_x(const float* __restrict__ X, u16* __restrict__ Xb) {
    int i = (blockIdx.x * 256 + threadIdx.x) * 4;
    f32x4 v = *reinterpret_cast<const f32x4*>(X + i);
    u16x4 o;
    #pragma unroll
    for (int u = 0; u < 4; ++u) o[u] = f2bf(v[u]);
    *reinterpret_cast<u16x4*>(Xb + i) = o;
}

// ---------------------------------------------------------------------------
// W (K x N fp32, row-major) -> WT (N x K bf16). 32x32 LDS tile.
// ---------------------------------------------------------------------------
__global__ void transp_k(const float* __restrict__ W, u16* __restrict__ WT,
                         int K, int N) {
    __shared__ float t[32][33];
    const int tid = threadIdx.x;
    const int k0 = blockIdx.y * 32, n0 = blockIdx.x * 32;
    const int r = tid >> 3, c4 = (tid & 7) * 4;
    f32x4 v = *reinterpret_cast<const f32x4*>(W + (size_t)(k0 + r) * N + n0 + c4);
    #pragma unroll
    for (int u = 0; u < 4; ++u) t[r][c4 + u] = v[u];
    __syncthreads();
    u16x4 o;
    #pragma unroll
    for (int u = 0; u < 4; ++u) o[u] = f2bf(t[c4 + u][r]);
    *reinterpret_cast<u16x4*>(WT + (size_t)(n0 + r) * K + k0 + c4) = o;
}

// ---------------------------------------------------------------------------
// bf16 MFMA GEMM: C[M,N] = A[M,K] @ W[K,N], W given pre-transposed (Bt: N x K).
// ROUND 15 CHANGE: tile 128x128 -> 128x64. Round-14 arithmetic: Wo/Qproj
// grids were 256 blocks = exactly 1 block/CU (K/V: 64 = 1/4 machine) —
// occupancy capped by GRID SHAPE, every staging barrier stalls the CU.
// 128x64 doubles the grid (Wo/Qproj 512 = 2/CU; K/V 128) so a second
// resident block overlaps the barrier. BK=32 loop order unchanged ->
// per-output accumulation order identical -> absmax unchanged.
// 4 waves in 2x2, each wave a 64x32 sub-tile = 4x2 16x16 frags.
// Fragment mapping HW-validated (rounds 3/10). LDS rows stride 80 B.
// MODE 0: fp32 write to out[m][1024] (Wo GEMM)
// MODE 1: phase-rotate pairs via __shfl_xor(.,1), write bf16 (B,H,T,D)
// MODE 2: write bf16 (B,KVH,T,D)
// ---------------------------------------------------------------------------
template<int MODE>
__global__ __launch_bounds__(256, 3)
void mfma_gemm(const u16* __restrict__ A, int lda, int aoff,
               const u16* __restrict__ Bt, int Ktot,
               void* __restrict__ Cout, const float* __restrict__ angles)
{
    __shared__ __align__(16) unsigned char lds[15360];
    unsigned char* As = lds;            // 128 rows x 32 bf16, stride 80 B
    unsigned char* Bs = lds + 10240;    //  64 rows x 32 bf16, stride 80 B

    const int tid  = threadIdx.x;
    const int lane = tid & 63;
    const int w    = tid >> 6;
    const int wm   = w >> 1, wn = w & 1;
    const int lr   = lane & 15, lg = lane >> 4;
    const int m0   = blockIdx.y * 128;
    const int n0   = blockIdx.x * 64;

    f32x4 acc[4][2] = {};

    for (int k0 = 0; k0 < Ktot; k0 += 32) {
        __syncthreads();
        #pragma unroll
        for (int p = 0; p < 2; ++p) {
            int lin = tid + p * 256;          // 0..511
            int row = lin >> 2;               // 0..127
            int kc  = (lin & 3) * 8;          // 0,8,16,24
            u16x8 av = *reinterpret_cast<const u16x8*>(
                A + (size_t)(m0 + row) * lda + aoff + k0 + kc);
            *reinterpret_cast<u16x8*>(As + row * 80 + kc * 2) = av;
        }
        {
            int row = tid >> 2;               // 0..63
            int kc  = (tid & 3) * 8;
            u16x8 bv = *reinterpret_cast<const u16x8*>(
                Bt + (size_t)(n0 + row) * Ktot + k0 + kc);
            *reinterpret_cast<u16x8*>(Bs + row * 80 + kc * 2) = bv;
        }
        __syncthreads();

        bf16x8 af[4], bfr[2];
        #pragma unroll
        for (int mt = 0; mt < 4; ++mt)
            af[mt] = *reinterpret_cast<bf16x8*>(
                As + (wm * 64 + mt * 16 + lr) * 80 + lg * 16);
        #pragma unroll
        for (int nt = 0; nt < 2; ++nt)
            bfr[nt] = *reinterpret_cast<bf16x8*>(
                Bs + (wn * 32 + nt * 16 + lr) * 80 + lg * 16);
        #pragma unroll
        for (int mt = 0; mt < 4; ++mt)
            #pragma unroll
            for (int nt = 0; nt < 2; ++nt)
                acc[mt][nt] = __builtin_amdgcn_mfma_f32_16x16x32_bf16(
                    af[mt], bfr[nt], acc[mt][nt], 0, 0, 0);
    }

    // Epilogue. m = m0+wm*64+mt*16+lg*4+j ; n = n0+wn*32+nt*16+lr
    #pragma unroll
    for (int nt = 0; nt < 2; ++nt) {
        const int nbase = n0 + wn * 32 + nt * 16;   // multiple of 16
        float ca = 0.f, sa = 0.f;
        if (MODE == 1) {
            const int h = nbase >> 6;               // constant across lr (<64)
            ca = cosf(angles[h]);
            sa = sinf(angles[h]);
        }
        #pragma unroll
        for (int mt = 0; mt < 4; ++mt) {
            #pragma unroll
            for (int j = 0; j < 4; ++j) {
                const int m = m0 + wm * 64 + mt * 16 + lg * 4 + j;
                const int n = nbase + lr;
                const float v = acc[mt][nt][j];
                if (MODE == 0) {
                    ((float*)Cout)[(size_t)m * (TOK_ + POS_) + n] = v;
                } else if (MODE == 1) {
                    const float p = __shfl_xor(v, 1);   // partner column n^1
                    const float o = (lr & 1) ? (p * sa + v * ca)
                                             : (v * ca - p * sa);
                    const int b = m >> 11, t = m & (T_ - 1);
                    const int h = n >> 6, d = n & 63;
                    ((u16*)Cout)[(((size_t)(b * H_ + h)) * T_ + t) * D_ + d] = f2bf(o);
                } else {
                    const int b = m >> 11, t = m & (T_ - 1);
                    const int h = n >> 6, d = n & 63;
                    ((u16*)Cout)[(((size_t)(b * KVH_ + h)) * T_ + t) * D_ + d] = f2bf(v);
                }
            }
        }
    }
}

// ---------------------------------------------------------------------------
// Global -> register staging for one 64-key K/V tile (256 threads).
// Thread mapping identical to the validated round-10/12 staging.
// ---------------------------------------------------------------------------
__device__ inline void stage_load(const u16* __restrict__ Kp,
                                  const u16* __restrict__ Vp,
                                  int kv0, int tid,
                                  u16x8* kreg, u16x8* vreg)
{
    #pragma unroll
    for (int it = 0; it < 2; ++it) {
        int lin = tid + it * 256;
        int row = lin >> 3;
        kreg[it] = *reinterpret_cast<const u16x8*>(
            Kp + (size_t)(kv0 + row) * D_ + (lin & 7) * 8);
        int key = lin & 63;
        int d8  = (lin >> 6) * 8;
        vreg[it] = *reinterpret_cast<const u16x8*>(
            Vp + (size_t)(kv0 + key) * D_ + d8);
    }
}

// Register -> LDS staging (XOR-swizzled; K row-major, V transposed).
__device__ inline void stage_write(unsigned char* __restrict__ Ksb,
                                   unsigned char* __restrict__ Vtb,
                                   int tid, const u16x8* kreg, const u16x8* vreg)
{
    #pragma unroll
    for (int it = 0; it < 2; ++it) {
        int lin = tid + it * 256;
        int row = lin >> 3;
        int c16 = (lin & 7) * 16;
        *reinterpret_cast<u16x8*>(Ksb + ((row * 128 + c16) ^ ((row & 7) << 4))) = kreg[it];
        int key = lin & 63;
        int d8  = (lin >> 6) * 8;
        #pragma unroll
        for (int e = 0; e < 8; ++e) {
            int d = d8 + e;
            *reinterpret_cast<u16*>(
                Vtb + ((d * 128 + key * 2) ^ ((d & 7) << 4))) = (u16)vreg[it][e];
        }
    }
}

// ---------------------------------------------------------------------------
// MFMA bf16 flash attention (causal, ALiBi, "+1" denominator).
// Validated round-14 structure (91.4us): triangular pairing (33 tile-units
// per block, grid 16x32 = 512 = 2/CU) + T14 async staging with LDS dbuf
// (1 barrier/iter, HBM latency hidden under compute). UNCHANGED this round.
// ---------------------------------------------------------------------------
__global__ __launch_bounds__(256, 2)
void flash_mfma(const u16* __restrict__ Q, const u16* __restrict__ K,
                const u16* __restrict__ V, const float* __restrict__ slopes,
                u16* __restrict__ O)
{
    __shared__ __align__(16) unsigned char lds[40960];
    // [0..16384)   : K buffers (2 x 8192)
    // [16384..32768): V^T buffers (2 x 8192)
    // [32768..40960): P tiles, per-wave 2048
    unsigned char* Ps = lds + 32768;

    const int tid  = threadIdx.x;
    const int lane = tid & 63;
    const int w    = tid >> 6;
    const int lr   = lane & 15;
    const int lg   = lane >> 4;

    const int bh  = blockIdx.y;
    const int b   = bh >> 4;
    const int h   = bh & 15;
    const int kvh = h >> 2;              // GQA: h // (H/KVH)

    const float slope = expf(slopes[h]);

    const u16* Kp = K + ((size_t)(b * KVH_ + kvh)) * T_ * D_;
    const u16* Vp = V + ((size_t)(b * KVH_ + kvh)) * T_ * D_;

    unsigned char* Pw = Ps + w * 2048;   // 16 rows x 128 B, wave-private

    u16x8 kreg[2], vreg[2];
    int cur = 0;

    #pragma unroll 1
    for (int pass = 0; pass < 2; ++pass) {
        const int qt = pass ? (T_ / 64 - 1 - blockIdx.x) : blockIdx.x;
        const int q0 = qt * 64;

        const u16* Qp = Q + (((size_t)(b * H_ + h)) * T_ + q0 + w * 16) * D_;
        const bf16x8 qa0 = *reinterpret_cast<const bf16x8*>(Qp + lr * D_ + lg * 8);
        const bf16x8 qa1 = *reinterpret_cast<const bf16x8*>(Qp + lr * D_ + 32 + lg * 8);

        f32x4 acc[4] = {};
        float mrow[4], lrow[4];
        #pragma unroll
        for (int j = 0; j < 4; ++j) { mrow[j] = -INFINITY; lrow[j] = 0.f; }

        // Pass prologue: stage tile 0 into buffer `cur`.
        stage_load(Kp, Vp, 0, tid, kreg, vreg);
        __syncthreads();                 // prior readers of buffer `cur` done
        stage_write(lds + cur * 8192, lds + 16384 + cur * 8192, tid, kreg, vreg);

        for (int jt = 0; jt <= qt; ++jt) {
            __syncthreads();             // buffer `cur` staging visible to all
            if (jt < qt)                 // issue next tile's loads early (T14)
                stage_load(Kp, Vp, (jt + 1) * 64, tid, kreg, vreg);

            unsigned char* Ks = lds + cur * 8192;
            unsigned char* Vt = lds + 16384 + cur * 8192;
            const int kv0 = jt * 64;

            f32x4 s[4];
            #pragma unroll
            for (int n = 0; n < 4; ++n) {
                int krow = n * 16 + lr;
                int swz  = (krow & 7) << 4;
                bf16x8 kb0 = *reinterpret_cast<bf16x8*>(Ks + ((krow * 128 + lg * 16) ^ swz));
                bf16x8 kb1 = *reinterpret_cast<bf16x8*>(Ks + ((krow * 128 + 64 + lg * 16) ^ swz));
                f32x4 z = {};
                z    = __builtin_amdgcn_mfma_f32_16x16x32_bf16(qa0, kb0, z, 0, 0, 0);
                s[n] = __builtin_amdgcn_mfma_f32_16x16x32_bf16(qa1, kb1, z, 0, 0, 0);
            }

            const int qbase = q0 + w * 16 + lg * 4;
            #pragma unroll
            for (int j = 0; j < 4; ++j) {
                const int qr = qbase + j;
                float a[4];
                float tmax = -INFINITY;
                #pragma unroll
                for (int n = 0; n < 4; ++n) {
                    int kg = kv0 + n * 16 + lr;
                    float vsc = s[n][j] * 0.125f + slope * (float)(qr - kg);
                    vsc = (kg <= qr) ? vsc : -INFINITY;
                    a[n] = vsc;
                    tmax = fmaxf(tmax, vsc);
                }
                #pragma unroll
                for (int off = 1; off < 16; off <<= 1)
                    tmax = fmaxf(tmax, __shfl_xor(tmax, off));
                const float mnew = fmaxf(mrow[j], tmax);
                const float sc   = __expf(mrow[j] - mnew);   // -inf -> 0 first tile
                float rsum = 0.f;
                u16 pb[4];
                #pragma unroll
                for (int n = 0; n < 4; ++n) {
                    float p = __expf(a[n] - mnew);           // masked -> 0
                    rsum += p;
                    pb[n] = f2bf(p);
                }
                #pragma unroll
                for (int off = 1; off < 16; off <<= 1)
                    rsum += __shfl_xor(rsum, off);
                lrow[j] = lrow[j] * sc + rsum;
                mrow[j] = mnew;
                #pragma unroll
                for (int dt = 0; dt < 4; ++dt) acc[dt][j] *= sc;
                const int prow = lg * 4 + j;
                #pragma unroll
                for (int n = 0; n < 4; ++n)
                    *reinterpret_cast<u16*>(
                        Pw + ((prow * 128 + (n * 16 + lr) * 2) ^ ((prow & 7) << 4))) = pb[n];
            }

            #pragma unroll
            for (int kh = 0; kh < 2; ++kh) {
                bf16x8 pa = *reinterpret_cast<bf16x8*>(
                    Pw + ((lr * 128 + kh * 64 + lg * 16) ^ ((lr & 7) << 4)));
                #pragma unroll
                for (int dt = 0; dt < 4; ++dt) {
                    int drow = dt * 16 + lr;
                    bf16x8 vb = *reinterpret_cast<bf16x8*>(
                        Vt + ((drow * 128 + kh * 64 + lg * 16) ^ ((drow & 7) << 4)));
                    acc[dt] = __builtin_amdgcn_mfma_f32_16x16x32_bf16(pa, vb, acc[dt], 0, 0, 0);
                }
            }

            if (jt < qt) {               // write next tile to the other buffer
                stage_write(lds + (cur ^ 1) * 8192, lds + 16384 + (cur ^ 1) * 8192,
                            tid, kreg, vreg);
                cur ^= 1;
            }
        }

        // epilogue: denom = 1 + l, write bf16 (B,T,H*D)
        u16* Op = O + ((size_t)b * T_ + q0 + w * 16) * (H_ * D_) + h * 64;
        #pragma unroll
        for (int j = 0; j < 4; ++j) {
            const float inv = 1.0f / (1.0f + lrow[j]);
            const int r = lg * 4 + j;
            #pragma unroll
            for (int dt = 0; dt < 4; ++dt)
                Op[(size_t)r * (H_ * D_) + dt * 16 + lr] = f2bf(acc[dt][j] * inv);
        }
    }
}

// ---------------------------------------------------------------------------
// Launcher. ws layout (u16 elems): xb 4M | Qb 4M | Kb 1M | Vb 1M | AttO 4M |
// WqT 512K | WkT 128K | WvT 128K | WoT 1M  (~31.7 MB). All regions written
// every call before read (ws is re-poisoned each timed launch).
// ---------------------------------------------------------------------------
extern "C" void kernel_launch(void* const* d_in, const int* in_sizes, int n_in,
                              void* d_out, int out_size, void* d_ws, size_t ws_size,
                              hipStream_t stream)
{
    const float* x      = (const float*)d_in[0];
    const float* Wq     = (const float*)d_in[1];
    const float* Wk     = (const float*)d_in[2];
    const float* Wv     = (const float*)d_in[3];
    const float* Wo     = (const float*)d_in[4];
    const float* ang    = (const float*)d_in[5];
    const float* slopes = (const float*)d_in[6];
    float* out = (float*)d_out;

    u16* xb   = (u16*)d_ws;
    u16* Qb   = xb   + (size_t)4096 * 1024;
    u16* Kb   = Qb   + (size_t)B_ * H_ * T_ * D_;
    u16* Vb   = Kb   + (size_t)B_ * KVH_ * T_ * D_;
    u16* AttO = Vb   + (size_t)B_ * KVH_ * T_ * D_;
    u16* WqT  = AttO + (size_t)4096 * 1024;
    u16* WkT  = WqT  + (size_t)1024 * 512;
    u16* WvT  = WkT  + (size_t)256 * 512;
    u16* WoT  = WvT  + (size_t)256 * 512;

    // Prologue: convert x, transpose+convert weights
    cvt_x<<<4096, 256, 0, stream>>>(x, xb);
    transp_k<<<dim3(1024 / 32, 512 / 32), 256, 0, stream>>>(Wq, WqT, 512, 1024);
    transp_k<<<dim3(256 / 32, 512 / 32), 256, 0, stream>>>(Wk, WkT, 512, 256);
    transp_k<<<dim3(256 / 32, 512 / 32), 256, 0, stream>>>(Wv, WvT, 512, 256);
    transp_k<<<dim3(1024 / 32, 1024 / 32), 256, 0, stream>>>(Wo, WoT, 1024, 1024);

    // Projections (bf16 MFMA, 128x64 tiles -> 2 blocks/CU on the big GEMMs)
    mfma_gemm<1><<<dim3(1024 / 64, 32), 256, 0, stream>>>(xb, 1024, 512, WqT, 512, Qb, ang);
    mfma_gemm<2><<<dim3(256 / 64, 32), 256, 0, stream>>>(xb, 1024, 512, WkT, 512, Kb, nullptr);
    mfma_gemm<2><<<dim3(256 / 64, 32), 256, 0, stream>>>(xb, 1024, 0,   WvT, 512, Vb, nullptr);

    // Flash attention (paired tiles + T14 dbuf staging) -> AttO bf16
    flash_mfma<<<dim3(T_ / 128, B_ * H_), 256, 0, stream>>>(Qb, Kb, Vb, slopes, AttO);

    // out = AttO @ Wo (bf16 MFMA, fp32 out)
    mfma_gemm<0><<<dim3(1024 / 64, 32), 256, 0, stream>>>(AttO, 1024, 0, WoT, 1024, out, nullptr);
}